// Round 8
// baseline (79.684 us; speedup 1.0000x reference)
//
#include <hip/hip_runtime.h>
#include <hip/hip_bf16.h>
#include <math.h>

#define NROW 8192
#define DIM  128
#define BM   64
#define BN   128
#define NTILES 4160         // sum_{tr<128} (64 - (tr>>1))
#define NT4    (NTILES * 4) // per-wave results = 16640 = 32 * 520
#define NRED   32
#define PERRED (NT4 / NRED) // 520

typedef __bf16 bf16x8 __attribute__((ext_vector_type(8)));
typedef float  f32x4  __attribute__((ext_vector_type(4)));

#define G2     369.3299304675746f   /* 256 * log2(e): logits in base-2 */
#define QPOS   (0.9375f * G2)       /* xp = G2*s^2 - 2*G2*s + QPOS     */
#define QNEG   (-0.0625f * G2)      /* xn = G2*t^2 + QNEG, t=max(s,-.25)*/
#define NEGBIG (-3.0e38f)
#define MSENT  (-4000.0f)           /* empty-class sentinel (s=0 there) */

// ---- Kernel H: label histogram + exclusive prefix -> cursor[64] ----
__global__ __launch_bounds__(256)
void hist_kernel(const int* __restrict__ lab, int* __restrict__ cursor) {
    __shared__ int h[4][64];
    const int tid  = threadIdx.x;
    const int w    = tid >> 6;
    const int lane = tid & 63;
    h[w][lane] = 0;
    __syncthreads();
    for (int i = tid; i < NROW; i += 256)
        atomicAdd(&h[w][lab[i]], 1);
    __syncthreads();
    if (tid < 64) {
        int tot = h[0][tid] + h[1][tid] + h[2][tid] + h[3][tid];
        int v = tot;
        #pragma unroll
        for (int off = 1; off < 64; off <<= 1) {
            int u = __shfl_up(v, off, 64);
            if (tid >= off) v += u;
        }
        cursor[tid] = v - tot;   // exclusive prefix
    }
}

// ---- Kernel A: normalize rows -> bf16, scattered into label-sorted order ----
__global__ __launch_bounds__(256)
void prep_kernel(const float* __restrict__ f, const int* __restrict__ lab,
                 int* __restrict__ cursor,
                 __hip_bfloat16* __restrict__ fhi, int* __restrict__ labS) {
    int row  = blockIdx.x * 4 + (threadIdx.x >> 6);
    int lane = threadIdx.x & 63;
    float2 v = ((const float2*)(f + (size_t)row * DIM))[lane];
    float ss = v.x * v.x + v.y * v.y;
    #pragma unroll
    for (int off = 32; off; off >>= 1) ss += __shfl_xor(ss, off, 64);
    float inv = 1.0f / fmaxf(sqrtf(ss), 1e-12f);
    int l = lab[row];
    int dest = 0;
    if (lane == 0) dest = atomicAdd(&cursor[l], 1);
    dest = __shfl(dest, 0, 64);
    __hip_bfloat162 hv;
    hv.x = __float2bfloat16(v.x * inv);
    hv.y = __float2bfloat16(v.y * inv);
    ((__hip_bfloat162*)(fhi + (size_t)dest * DIM))[lane] = hv;
    if (lane == 0) labS[dest] = l;
}

// first linear bid of row-tile tr (tc starts at tr>>1)
__device__ __forceinline__ int tstart(int tr) {
    int m = tr >> 1;
    int f = m * m - ((tr & 1) ? 0 : m);
    return 64 * tr - f;
}

// ---- Kernel B: MFMA sim + sorted-label specialized LSE epilogue ----
__global__ __launch_bounds__(256, 4)
void sim_kernel(const __hip_bfloat16* __restrict__ fhi,
                const int* __restrict__ labS,
                float4* __restrict__ blockRes) {
    const int tid  = threadIdx.x;
    const int w    = tid >> 6;
    const int lane = tid & 63;
    const int lrow = lane & 15;
    const int lk   = lane >> 4;

    // triangular decode: bid -> (tr, tc), tc >= tr>>1
    int bid = blockIdx.x;
    float sa = fmaxf(16384.f - 4.f * (float)bid, 0.f);
    int tr = 128 - (int)sqrtf(sa);
    if (tr > 127) tr = 127;
    if (tr < 0) tr = 0;
    while (tr > 0 && bid < tstart(tr)) --tr;
    while (bid >= tstart(tr + 1)) ++tr;
    const int tc = (tr >> 1) + (bid - tstart(tr));

    const int rowBase = tr * BM;
    const int colBase = tc * BN;

    // purity probe (uniform): sorted labels => all-neg iff row-end label != col-start label
    const int labRowEnd = labS[rowBase + BM - 1];
    const int labCol0   = labS[colBase];
    const bool edge  = (tc == (tr >> 1));
    const bool mixed = edge || (labRowEnd == labCol0);

    __shared__ __align__(16) char smem[24 * 1024]; // A[64][64] + B[128][64] bf16
    __shared__ int labA[BM];
    __shared__ int labB[BN];

    if (tid < BM)            labA[tid] = labS[rowBase + tid];
    else if (tid < BM + BN)  labB[tid - BM] = labS[colBase + (tid - BM)];

    f32x4 acc[4][2];
    #pragma unroll
    for (int mi = 0; mi < 4; ++mi)
        #pragma unroll
        for (int ni = 0; ni < 2; ++ni) acc[mi][ni] = (f32x4){0.f, 0.f, 0.f, 0.f};

    const int ncol0 = w * 32;                     // 1x4 wave grid: 64x32 per wave
    const int rsub = lane >> 3;                   // row within 8-row segment
    const int kbs  = 16 * ((lane & 7) ^ rsub);    // pre-swizzled source byte

    for (int kc = 0; kc < 2; ++kc) {   // two K=64 chunks
        #pragma unroll
        for (int t = 0; t < 6; ++t) {
            int seg = w * 6 + t;          // 0..23 segments of 1KB (A:0-7, B:8-23)
            char* ldsb = smem + seg * 1024;
            int grow = (seg < 8) ? (rowBase + (seg & 7) * 8 + rsub)
                                 : (colBase + (seg - 8) * 8 + rsub);
            const char* g = (const char*)fhi + (size_t)grow * 256 + kc * 128 + kbs;
            __builtin_amdgcn_global_load_lds(
                (const __attribute__((address_space(1))) void*)g,
                (__attribute__((address_space(3))) void*)ldsb, 16, 0, 0);
        }
        __syncthreads();   // drains vmcnt

        const char* As = smem;
        const char* Bs = smem + 8192;
        #pragma unroll
        for (int c = 0; c < 2; ++c) {
            int kb = c * 64 + lk * 16;
            bf16x8 bfr[2];
            #pragma unroll
            for (int ni = 0; ni < 2; ++ni) {
                int rb = ncol0 + ni * 16 + lrow;
                bfr[ni] = *(const bf16x8*)(Bs + rb * 128 + (kb ^ ((rb & 7) << 4)));
            }
            #pragma unroll
            for (int mi = 0; mi < 4; ++mi) {
                int ra = mi * 16 + lrow;
                bf16x8 afr = *(const bf16x8*)(As + ra * 128 + (kb ^ ((ra & 7) << 4)));
                #pragma unroll
                for (int ni = 0; ni < 2; ++ni)
                    acc[mi][ni] = __builtin_amdgcn_mfma_f32_16x16x32_bf16(afr, bfr[ni], acc[mi][ni], 0, 0, 0);
            }
        }
        if (kc == 0) __syncthreads();   // protect LDS reuse before chunk 1 staging
    }

    float4 res;
    if (!mixed) {
        // ======== PURE-NEGATIVE tile (~96%): 5 VALU + 1 exp2 per element ======
        float mx = 0.0f;   // max |t|, t in [-0.25, 1]
        #pragma unroll
        for (int mi = 0; mi < 4; ++mi)
            #pragma unroll
            for (int ni = 0; ni < 2; ++ni)
                #pragma unroll
                for (int r = 0; r < 4; ++r) {
                    float t = fmaxf(acc[mi][ni][r], -0.25f);
                    acc[mi][ni][r] = t;
                    mx = fmaxf(mx, fabsf(t));
                }
        #pragma unroll
        for (int off = 32; off; off >>= 1)
            mx = fmaxf(mx, __shfl_xor(mx, off, 64));
        const float zc = -G2 * mx * mx;     // z = G2*t^2 - G2*mx^2  (<= 0)
        float sn = 0.f;
        #pragma unroll
        for (int mi = 0; mi < 4; ++mi)
            #pragma unroll
            for (int ni = 0; ni < 2; ++ni)
                #pragma unroll
                for (int r = 0; r < 4; ++r) {
                    float t = acc[mi][ni][r];
                    sn += __builtin_amdgcn_exp2f(fmaf(G2, t * t, zc));
                }
        #pragma unroll
        for (int off = 32; off; off >>= 1)
            sn += __shfl_xor(sn, off, 64);
        res = make_float4(MSENT, 0.f, fmaf(G2, mx * mx, QNEG), sn);
    } else {
        // ======== MIXED / EDGE tile (~4%): lean general path ========
        float minp = 1e30f;    // min s over valid positives (xp decreasing in s)
        float mabs = -1.0f;    // max |t| over valid negatives
        int lbv[2];
        #pragma unroll
        for (int ni = 0; ni < 2; ++ni) lbv[ni] = labB[ncol0 + ni * 16 + lrow];

#define PASS_AB(EDGEF)                                                         \
    _Pragma("unroll")                                                          \
    for (int mi = 0; mi < 4; ++mi) {                                           \
        int4 la4 = *(const int4*)&labA[mi * 16 + lk * 4];                      \
        const int la[4] = {la4.x, la4.y, la4.z, la4.w};                        \
        _Pragma("unroll")                                                      \
        for (int ni = 0; ni < 2; ++ni) {                                       \
            _Pragma("unroll")                                                  \
            for (int r = 0; r < 4; ++r) {                                      \
                float s = acc[mi][ni][r];                                      \
                bool pos = (la[r] == lbv[ni]);                                 \
                float t = fmaxf(s, -0.25f);                                    \
                bool valid = true;                                             \
                if (EDGEF) {                                                   \
                    int ig = rowBase + mi * 16 + lk * 4 + r;                   \
                    int jg = colBase + ncol0 + ni * 16 + lrow;                 \
                    valid = (jg > ig);                                         \
                    pos = pos && valid;                                        \
                }                                                              \
                float u = pos ? s : t;                                         \
                minp = fminf(minp, pos ? s : 1e30f);                           \
                bool nm = EDGEF ? (valid && !pos) : !pos;                      \
                mabs = fmaxf(mabs, nm ? fabsf(t) : -1.0f);                     \
                acc[mi][ni][r] = u;                                            \
            }                                                                  \
        }                                                                      \
    }
        if (edge) { PASS_AB(true) } else { PASS_AB(false) }
#undef PASS_AB

        #pragma unroll
        for (int off = 32; off; off >>= 1) {
            minp = fminf(minp, __shfl_xor(minp, off, 64));
            mabs = fmaxf(mabs, __shfl_xor(mabs, off, 64));
        }
        const float Mp = (minp < 2.0f)
            ? fmaf(G2, minp * minp, fmaf(-2.0f * G2, minp, QPOS)) : MSENT;
        const float Mn = (mabs >= 0.0f) ? fmaf(G2, mabs * mabs, QNEG) : MSENT;
        const float qph = QPOS - Mp;
        const float qnh = QNEG - Mn;
        float sp = 0.f, sn = 0.f;

#define PASS_B(EDGEF)                                                          \
    _Pragma("unroll")                                                          \
    for (int mi = 0; mi < 4; ++mi) {                                           \
        int4 la4 = *(const int4*)&labA[mi * 16 + lk * 4];                      \
        const int la[4] = {la4.x, la4.y, la4.z, la4.w};                        \
        _Pragma("unroll")                                                      \
        for (int ni = 0; ni < 2; ++ni) {                                       \
            _Pragma("unroll")                                                  \
            for (int r = 0; r < 4; ++r) {                                      \
                float u = acc[mi][ni][r];                                      \
                bool pos = (la[r] == lbv[ni]);                                 \
                float P  = pos ? (-2.0f * G2) : 0.0f;                          \
                float Qh = pos ? qph : qnh;                                    \
                float e = __builtin_amdgcn_exp2f(                              \
                              fmaf(G2, u * u, fmaf(P, u, Qh)));                \
                if (EDGEF) {                                                   \
                    int ig = rowBase + mi * 16 + lk * 4 + r;                   \
                    int jg = colBase + ncol0 + ni * 16 + lrow;                 \
                    e = (jg > ig) ? e : 0.f;                                   \
                }                                                              \
                float ep = pos ? e : 0.f;                                      \
                sp += ep;                                                      \
                sn += (e - ep);                                                \
            }                                                                  \
        }                                                                      \
    }
        if (edge) { PASS_B(true) } else { PASS_B(false) }
#undef PASS_B

        #pragma unroll
        for (int off = 32; off; off >>= 1) {
            sp += __shfl_xor(sp, off, 64);
            sn += __shfl_xor(sn, off, 64);
        }
        res = make_float4(Mp, sp, Mn, sn);
    }
    if (lane == 0) blockRes[bid * 4 + w] = res;
}

// ---- merge helper: (m,s) pairs represent s * 2^m ----
__device__ __forceinline__ void merge2(float& m, float& s, float mo, float so) {
    float M = fmaxf(m, mo);
    s = s * __builtin_amdgcn_exp2f(m - M) + so * __builtin_amdgcn_exp2f(mo - M);
    m = M;
}

// ---- Kernel C1: parallel tree reduce 16640 -> 32 ----
__global__ __launch_bounds__(256)
void reduce_kernel(const float4* __restrict__ in, float4* __restrict__ partial) {
    __shared__ float red[4][4];
    const int tid  = threadIdx.x;
    const int base = blockIdx.x * PERRED;
    float mp = NEGBIG, sp = 0.f, mn = NEGBIG, sn = 0.f;
    for (int i = tid; i < PERRED; i += 256) {
        float4 v = in[base + i];
        merge2(mp, sp, v.x, v.y);
        merge2(mn, sn, v.z, v.w);
    }
    #pragma unroll
    for (int off = 32; off; off >>= 1) {
        float mo = __shfl_xor(mp, off, 64), so = __shfl_xor(sp, off, 64);
        merge2(mp, sp, mo, so);
        float mo2 = __shfl_xor(mn, off, 64), so2 = __shfl_xor(sn, off, 64);
        merge2(mn, sn, mo2, so2);
    }
    const int wv = tid >> 6;
    if ((tid & 63) == 0) {
        red[wv][0] = mp; red[wv][1] = sp; red[wv][2] = mn; red[wv][3] = sn;
    }
    __syncthreads();
    if (tid == 0) {
        mp = red[0][0]; sp = red[0][1]; mn = red[0][2]; sn = red[0][3];
        #pragma unroll
        for (int q = 1; q < 4; ++q) {
            merge2(mp, sp, red[q][0], red[q][1]);
            merge2(mn, sn, red[q][2], red[q][3]);
        }
        partial[blockIdx.x] = make_float4(mp, sp, mn, sn);
    }
}

// ---- Kernel C2: merge 32 partials + softplus ----
__global__ __launch_bounds__(64)
void finalize_kernel(const float4* __restrict__ partial, float* __restrict__ out) {
    const int lane = threadIdx.x;
    float mp = NEGBIG, sp = 0.f, mn = NEGBIG, sn = 0.f;
    if (lane < NRED) {
        float4 v = partial[lane];
        mp = v.x; sp = v.y; mn = v.z; sn = v.w;
    }
    #pragma unroll
    for (int off = 32; off; off >>= 1) {
        float mo = __shfl_xor(mp, off, 64), so = __shfl_xor(sp, off, 64);
        merge2(mp, sp, mo, so);
        float mo2 = __shfl_xor(mn, off, 64), so2 = __shfl_xor(sn, off, 64);
        merge2(mn, sn, mo2, so2);
    }
    if (lane == 0) {
        const double LN2 = 0.6931471805599453;
        double lse_p = ((double)mp + log2((double)sp)) * LN2;
        double lse_n = ((double)mn + log2((double)sn)) * LN2;
        double xx = lse_p + lse_n;
        double r = (xx > 30.0) ? xx : log1p(exp(xx));
        out[0] = (float)r;
    }
}

extern "C" void kernel_launch(void* const* d_in, const int* in_sizes, int n_in,
                              void* d_out, int out_size, void* d_ws, size_t ws_size,
                              hipStream_t stream) {
    const float* f   = (const float*)d_in[0];
    const int*   lab = (const int*)d_in[1];
    float*  out      = (float*)d_out;

    __hip_bfloat16* fhi = (__hip_bfloat16*)d_ws;                      // 2 MB
    int* labS    = (int*)((char*)d_ws + 2u * 1024 * 1024);            // 32 KB
    int* cursor  = (int*)((char*)d_ws + 3u * 1024 * 1024);            // 64 ints
    float4* blockRes = (float4*)((char*)d_ws + 4u * 1024 * 1024);     // 16640
    float4* partial  = (float4*)((char*)d_ws + 8u * 1024 * 1024);     // 32

    hist_kernel<<<1, 256, 0, stream>>>(lab, cursor);
    prep_kernel<<<NROW / 4, 256, 0, stream>>>(f, lab, cursor, fhi, labS);
    sim_kernel<<<NTILES, 256, 0, stream>>>(fhi, labS, blockRes);
    reduce_kernel<<<NRED, 256, 0, stream>>>(blockRes, partial);
    finalize_kernel<<<1, 64, 0, stream>>>(partial, out);
}

// Round 9
// 54.213 us; speedup vs baseline: 1.4698x; 1.4698x over previous
//
#include <hip/hip_runtime.h>
#include <hip/hip_bf16.h>
#include <math.h>

#define NROW 8192
#define DIM  128
#define BM   64
#define BN   128
#define NTILES 4160         // sum_{tr<128} (64 - (tr>>1))
#define GRID   832          // persistent blocks; 4160 = 832 * 5
#define TPB    5            // tiles per block
#define NT4    (NTILES * 4) // per-wave results = 16640 = 32 * 520
#define NRED   32
#define PERRED (NT4 / NRED) // 520

typedef __bf16 bf16x8 __attribute__((ext_vector_type(8)));
typedef float  f32x4  __attribute__((ext_vector_type(4)));

#define G2     369.3299304675746f   /* 256 * log2(e): logits in base-2 */
#define QPOS   (0.9375f * G2)       /* xp = G2*s^2 - 2*G2*s + QPOS      */
#define QNEG   (-0.0625f * G2)      /* xn = G2*t^2 + QNEG, t=max(s,-.25)*/
#define NEGBIG (-3.0e38f)
#define MSENT  (-4000.0f)           /* empty-class sentinel */
#define CSTR   32                   /* cursor stride: 1 counter / 128B  */

// ---- Kernel H: label histogram + exclusive prefix -> padded cursor ----
__global__ __launch_bounds__(256)
void hist_kernel(const int* __restrict__ lab, int* __restrict__ cursor) {
    __shared__ int h[4][64];
    const int tid  = threadIdx.x;
    const int w    = tid >> 6;
    const int lane = tid & 63;
    h[w][lane] = 0;
    __syncthreads();
    for (int i = tid; i < NROW; i += 256)
        atomicAdd(&h[w][lab[i]], 1);
    __syncthreads();
    if (tid < 64) {
        int tot = h[0][tid] + h[1][tid] + h[2][tid] + h[3][tid];
        int v = tot;
        #pragma unroll
        for (int off = 1; off < 64; off <<= 1) {
            int u = __shfl_up(v, off, 64);
            if (tid >= off) v += u;
        }
        cursor[tid * CSTR] = v - tot;   // exclusive prefix, cacheline-padded
    }
}

// ---- Kernel A: normalize rows -> bf16, scattered into label-sorted order ----
__global__ __launch_bounds__(256)
void prep_kernel(const float* __restrict__ f, const int* __restrict__ lab,
                 int* __restrict__ cursor,
                 __hip_bfloat16* __restrict__ fhi, int* __restrict__ labS) {
    int row  = blockIdx.x * 4 + (threadIdx.x >> 6);
    int lane = threadIdx.x & 63;
    float2 v = ((const float2*)(f + (size_t)row * DIM))[lane];
    float ss = v.x * v.x + v.y * v.y;
    #pragma unroll
    for (int off = 32; off; off >>= 1) ss += __shfl_xor(ss, off, 64);
    float inv = 1.0f / fmaxf(sqrtf(ss), 1e-12f);
    int l = lab[row];
    int dest = 0;
    if (lane == 0) dest = atomicAdd(&cursor[l * CSTR], 1);
    dest = __shfl(dest, 0, 64);
    __hip_bfloat162 hv;
    hv.x = __float2bfloat16(v.x * inv);
    hv.y = __float2bfloat16(v.y * inv);
    ((__hip_bfloat162*)(fhi + (size_t)dest * DIM))[lane] = hv;
    if (lane == 0) labS[dest] = l;
}

// first linear bid of row-tile tr (tc starts at tr>>1)
__device__ __forceinline__ int tstart(int tr) {
    int m = tr >> 1;
    int f = m * m - ((tr & 1) ? 0 : m);
    return 64 * tr - f;
}

__device__ __forceinline__ void decode_tile(int bid, int& otr, int& otc) {
    float sa = fmaxf(16384.f - 4.f * (float)bid, 0.f);
    int tr = 128 - (int)sqrtf(sa);
    if (tr > 127) tr = 127;
    if (tr < 0) tr = 0;
    while (tr > 0 && bid < tstart(tr)) --tr;
    while (bid >= tstart(tr + 1)) ++tr;
    otr = tr;
    otc = (tr >> 1) + (bid - tstart(tr));
}

// ---- Kernel B: persistent, double-buffered, counted-vmcnt pipelined sim ----
__global__ __launch_bounds__(256, 3)
void sim_kernel(const __hip_bfloat16* __restrict__ fhi,
                const int* __restrict__ labS,
                float4* __restrict__ blockRes) {
    const int tid  = threadIdx.x;
    const int w    = tid >> 6;
    const int lane = tid & 63;
    const int lrow = lane & 15;
    const int lk   = lane >> 4;
    const int rsub = lane >> 3;                   // row within 8-row segment
    const int kbs  = 16 * ((lane & 7) ^ rsub);    // pre-swizzled source byte

    __shared__ __align__(16) char smem[2][24 * 1024]; // 2 x (A[64][64]+B[128][64])

    // stage one 24KB K-chunk (kc) of tile (rb,cb) into buffer buf: 6 loads/wave
    auto STAGE = [&](int buf, int rb, int cb, int kc) {
        #pragma unroll
        for (int t = 0; t < 6; ++t) {
            int seg = w * 6 + t;          // 0..23 segments of 1KB (A:0-7, B:8-23)
            char* ldsb = &smem[buf][seg * 1024];
            int grow = (seg < 8) ? (rb + (seg & 7) * 8 + rsub)
                                 : (cb + (seg - 8) * 8 + rsub);
            const char* g = (const char*)fhi + (size_t)grow * 256 + kc * 128 + kbs;
            __builtin_amdgcn_global_load_lds(
                (const __attribute__((address_space(1))) void*)g,
                (__attribute__((address_space(3))) void*)ldsb, 16, 0, 0);
        }
    };

    f32x4 acc[4][2];
    #pragma unroll
    for (int mi = 0; mi < 4; ++mi)
        #pragma unroll
        for (int ni = 0; ni < 2; ++ni) acc[mi][ni] = (f32x4){0.f, 0.f, 0.f, 0.f};

    const int ncol0 = w * 32;   // 1x4 wave grid: 64x32 per wave

    auto COMPUTE = [&](int buf) {
        const char* As = smem[buf];
        const char* Bs = smem[buf] + 8192;
        #pragma unroll
        for (int c = 0; c < 2; ++c) {
            int kb = c * 64 + lk * 16;
            bf16x8 bfr[2];
            #pragma unroll
            for (int ni = 0; ni < 2; ++ni) {
                int rb = ncol0 + ni * 16 + lrow;
                bfr[ni] = *(const bf16x8*)(Bs + rb * 128 + (kb ^ ((rb & 7) << 4)));
            }
            #pragma unroll
            for (int mi = 0; mi < 4; ++mi) {
                int ra = mi * 16 + lrow;
                bf16x8 afr = *(const bf16x8*)(As + ra * 128 + (kb ^ ((ra & 7) << 4)));
                #pragma unroll
                for (int ni = 0; ni < 2; ++ni)
                    acc[mi][ni] = __builtin_amdgcn_mfma_f32_16x16x32_bf16(afr, bfr[ni], acc[mi][ni], 0, 0, 0);
            }
        }
    };

    int tile = blockIdx.x;
    int tr, tc;
    decode_tile(tile, tr, tc);
    int rowBase = tr * BM, colBase = tc * BN;

    STAGE(0, rowBase, colBase, 0);   // 6 outstanding
    STAGE(1, rowBase, colBase, 1);   // 12 outstanding

    for (int i = 0; i < TPB; ++i) {
        const bool more = (i + 1 < TPB);
        int ntile = tile + GRID, ntr = 0, ntc = 0, nrb = 0, ncb = 0;
        if (more) { decode_tile(ntile, ntr, ntc); nrb = ntr * BM; ncb = ntc * BN; }

        // ---- chunk 0 ----  (buf0's 6 loads are oldest; >=6 younger ops exist)
        asm volatile("s_waitcnt vmcnt(6)" ::: "memory");
        __builtin_amdgcn_s_barrier();
        COMPUTE(0);
        asm volatile("s_waitcnt lgkmcnt(0)" ::: "memory");
        __builtin_amdgcn_s_barrier();
        if (more) STAGE(0, nrb, ncb, 0);

        // ---- chunk 1 ----
        if (more) asm volatile("s_waitcnt vmcnt(6)" ::: "memory");
        else      asm volatile("s_waitcnt vmcnt(0)" ::: "memory");  // tail: drain
        __builtin_amdgcn_s_barrier();
        COMPUTE(1);
        asm volatile("s_waitcnt lgkmcnt(0)" ::: "memory");
        __builtin_amdgcn_s_barrier();
        if (more) STAGE(1, nrb, ncb, 1);

        // ---- epilogue for current tile (overlaps next tile's staging) ----
        const bool edge = (tc == (tr >> 1));
        const int labRowEnd = labS[rowBase + BM - 1];   // uniform -> s_load
        const int labCol0   = labS[colBase];
        const bool mixed = edge || (labRowEnd == labCol0);

        float4 res;
        if (!mixed) {
            // pure-negative tile (~96%)
            float mx = 0.0f;
            #pragma unroll
            for (int mi = 0; mi < 4; ++mi)
                #pragma unroll
                for (int ni = 0; ni < 2; ++ni)
                    #pragma unroll
                    for (int r = 0; r < 4; ++r) {
                        float t = fmaxf(acc[mi][ni][r], -0.25f);
                        acc[mi][ni][r] = t;
                        mx = fmaxf(mx, fabsf(t));
                    }
            #pragma unroll
            for (int off = 32; off; off >>= 1)
                mx = fmaxf(mx, __shfl_xor(mx, off, 64));
            const float zc = -G2 * mx * mx;
            float sn = 0.f;
            #pragma unroll
            for (int mi = 0; mi < 4; ++mi)
                #pragma unroll
                for (int ni = 0; ni < 2; ++ni)
                    #pragma unroll
                    for (int r = 0; r < 4; ++r) {
                        float t = acc[mi][ni][r];
                        sn += __builtin_amdgcn_exp2f(fmaf(G2, t * t, zc));
                    }
            #pragma unroll
            for (int off = 32; off; off >>= 1)
                sn += __shfl_xor(sn, off, 64);
            res = make_float4(MSENT, 0.f, fmaf(G2, mx * mx, QNEG), sn);
        } else {
            // mixed / edge tile (~4%)
            int lbv[2];
            #pragma unroll
            for (int ni = 0; ni < 2; ++ni)
                lbv[ni] = labS[colBase + ncol0 + ni * 16 + lrow];
            int4 laR[4];
            #pragma unroll
            for (int mi = 0; mi < 4; ++mi)
                laR[mi] = *(const int4*)&labS[rowBase + mi * 16 + lk * 4];

            float minp = 1e30f;    // min s over valid positives
            float mabs = -1.0f;    // max |t| over valid negatives

#define PASS_AB(EDGEF)                                                         \
    _Pragma("unroll")                                                          \
    for (int mi = 0; mi < 4; ++mi) {                                           \
        const int la[4] = {laR[mi].x, laR[mi].y, laR[mi].z, laR[mi].w};        \
        _Pragma("unroll")                                                      \
        for (int ni = 0; ni < 2; ++ni) {                                       \
            _Pragma("unroll")                                                  \
            for (int r = 0; r < 4; ++r) {                                      \
                float s = acc[mi][ni][r];                                      \
                bool pos = (la[r] == lbv[ni]);                                 \
                float t = fmaxf(s, -0.25f);                                    \
                bool valid = true;                                             \
                if (EDGEF) {                                                   \
                    int ig = rowBase + mi * 16 + lk * 4 + r;                   \
                    int jg = colBase + ncol0 + ni * 16 + lrow;                 \
                    valid = (jg > ig);                                         \
                    pos = pos && valid;                                        \
                }                                                              \
                float u = pos ? s : t;                                         \
                minp = fminf(minp, pos ? s : 1e30f);                           \
                bool nm = EDGEF ? (valid && !pos) : !pos;                      \
                mabs = fmaxf(mabs, nm ? fabsf(t) : -1.0f);                     \
                acc[mi][ni][r] = u;                                            \
            }                                                                  \
        }                                                                      \
    }
            if (edge) { PASS_AB(true) } else { PASS_AB(false) }
#undef PASS_AB

            #pragma unroll
            for (int off = 32; off; off >>= 1) {
                minp = fminf(minp, __shfl_xor(minp, off, 64));
                mabs = fmaxf(mabs, __shfl_xor(mabs, off, 64));
            }
            const float Mp = (minp < 2.0f)
                ? fmaf(G2, minp * minp, fmaf(-2.0f * G2, minp, QPOS)) : MSENT;
            const float Mn = (mabs >= 0.0f) ? fmaf(G2, mabs * mabs, QNEG) : MSENT;
            const float qph = QPOS - Mp;
            const float qnh = QNEG - Mn;
            float sp = 0.f, sn = 0.f;

#define PASS_B(EDGEF)                                                          \
    _Pragma("unroll")                                                          \
    for (int mi = 0; mi < 4; ++mi) {                                           \
        const int la[4] = {laR[mi].x, laR[mi].y, laR[mi].z, laR[mi].w};        \
        _Pragma("unroll")                                                      \
        for (int ni = 0; ni < 2; ++ni) {                                       \
            _Pragma("unroll")                                                  \
            for (int r = 0; r < 4; ++r) {                                      \
                float u = acc[mi][ni][r];                                      \
                bool pos = (la[r] == lbv[ni]);                                 \
                float P  = pos ? (-2.0f * G2) : 0.0f;                          \
                float Qh = pos ? qph : qnh;                                    \
                float e = __builtin_amdgcn_exp2f(                              \
                              fmaf(G2, u * u, fmaf(P, u, Qh)));                \
                if (EDGEF) {                                                   \
                    int ig = rowBase + mi * 16 + lk * 4 + r;                   \
                    int jg = colBase + ncol0 + ni * 16 + lrow;                 \
                    e = (jg > ig) ? e : 0.f;                                   \
                }                                                              \
                float ep = pos ? e : 0.f;                                      \
                sp += ep;                                                      \
                sn += (e - ep);                                                \
            }                                                                  \
        }                                                                      \
    }
            if (edge) { PASS_B(true) } else { PASS_B(false) }
#undef PASS_B

            #pragma unroll
            for (int off = 32; off; off >>= 1) {
                sp += __shfl_xor(sp, off, 64);
                sn += __shfl_xor(sn, off, 64);
            }
            res = make_float4(Mp, sp, Mn, sn);
        }
        if (lane == 0) blockRes[tile * 4 + w] = res;

        // reset accumulators, advance tile
        #pragma unroll
        for (int mi = 0; mi < 4; ++mi)
            #pragma unroll
            for (int ni = 0; ni < 2; ++ni) acc[mi][ni] = (f32x4){0.f, 0.f, 0.f, 0.f};
        tile = ntile; tr = ntr; tc = ntc; rowBase = nrb; colBase = ncb;
    }
}

// ---- merge helper: (m,s) pairs represent s * 2^m ----
__device__ __forceinline__ void merge2(float& m, float& s, float mo, float so) {
    float M = fmaxf(m, mo);
    s = s * __builtin_amdgcn_exp2f(m - M) + so * __builtin_amdgcn_exp2f(mo - M);
    m = M;
}

// ---- Kernel C1: parallel tree reduce 16640 -> 32 ----
__global__ __launch_bounds__(256)
void reduce_kernel(const float4* __restrict__ in, float4* __restrict__ partial) {
    __shared__ float red[4][4];
    const int tid  = threadIdx.x;
    const int base = blockIdx.x * PERRED;
    float mp = NEGBIG, sp = 0.f, mn = NEGBIG, sn = 0.f;
    for (int i = tid; i < PERRED; i += 256) {
        float4 v = in[base + i];
        merge2(mp, sp, v.x, v.y);
        merge2(mn, sn, v.z, v.w);
    }
    #pragma unroll
    for (int off = 32; off; off >>= 1) {
        float mo = __shfl_xor(mp, off, 64), so = __shfl_xor(sp, off, 64);
        merge2(mp, sp, mo, so);
        float mo2 = __shfl_xor(mn, off, 64), so2 = __shfl_xor(sn, off, 64);
        merge2(mn, sn, mo2, so2);
    }
    const int wv = tid >> 6;
    if ((tid & 63) == 0) {
        red[wv][0] = mp; red[wv][1] = sp; red[wv][2] = mn; red[wv][3] = sn;
    }
    __syncthreads();
    if (tid == 0) {
        mp = red[0][0]; sp = red[0][1]; mn = red[0][2]; sn = red[0][3];
        #pragma unroll
        for (int q = 1; q < 4; ++q) {
            merge2(mp, sp, red[q][0], red[q][1]);
            merge2(mn, sn, red[q][2], red[q][3]);
        }
        partial[blockIdx.x] = make_float4(mp, sp, mn, sn);
    }
}

// ---- Kernel C2: merge 32 partials + softplus ----
__global__ __launch_bounds__(64)
void finalize_kernel(const float4* __restrict__ partial, float* __restrict__ out) {
    const int lane = threadIdx.x;
    float mp = NEGBIG, sp = 0.f, mn = NEGBIG, sn = 0.f;
    if (lane < NRED) {
        float4 v = partial[lane];
        mp = v.x; sp = v.y; mn = v.z; sn = v.w;
    }
    #pragma unroll
    for (int off = 32; off; off >>= 1) {
        float mo = __shfl_xor(mp, off, 64), so = __shfl_xor(sp, off, 64);
        merge2(mp, sp, mo, so);
        float mo2 = __shfl_xor(mn, off, 64), so2 = __shfl_xor(sn, off, 64);
        merge2(mn, sn, mo2, so2);
    }
    if (lane == 0) {
        const double LN2 = 0.6931471805599453;
        double lse_p = ((double)mp + log2((double)sp)) * LN2;
        double lse_n = ((double)mn + log2((double)sn)) * LN2;
        double xx = lse_p + lse_n;
        double r = (xx > 30.0) ? xx : log1p(exp(xx));
        out[0] = (float)r;
    }
}

extern "C" void kernel_launch(void* const* d_in, const int* in_sizes, int n_in,
                              void* d_out, int out_size, void* d_ws, size_t ws_size,
                              hipStream_t stream) {
    const float* f   = (const float*)d_in[0];
    const int*   lab = (const int*)d_in[1];
    float*  out      = (float*)d_out;

    __hip_bfloat16* fhi = (__hip_bfloat16*)d_ws;                      // 2 MB
    int* labS    = (int*)((char*)d_ws + 2u * 1024 * 1024);            // 32 KB
    int* cursor  = (int*)((char*)d_ws + 3u * 1024 * 1024);            // 64*32 ints
    float4* blockRes = (float4*)((char*)d_ws + 4u * 1024 * 1024);     // 16640
    float4* partial  = (float4*)((char*)d_ws + 8u * 1024 * 1024);     // 32

    hist_kernel<<<1, 256, 0, stream>>>(lab, cursor);
    prep_kernel<<<NROW / 4, 256, 0, stream>>>(f, lab, cursor, fhi, labS);
    sim_kernel<<<GRID, 256, 0, stream>>>(fhi, labS, blockRes);
    reduce_kernel<<<NRED, 256, 0, stream>>>(blockRes, partial);
    finalize_kernel<<<1, 64, 0, stream>>>(partial, out);
}